// Round 2
// baseline (1159.887 us; speedup 1.0000x reference)
//
#include <hip/hip_runtime.h>

#define B_SZ 128
#define NPTS 2048
#define CATE 55

// prep: per-batch argmax of cls_score -> cid; zero the row-sum scratch.
__global__ __launch_bounds__(256) void prep_kernel(
    const float* __restrict__ cls, int* __restrict__ cid,
    float* __restrict__ sums, int nsums)
{
    int gt = blockIdx.x * 256 + threadIdx.x;
    if (gt < B_SZ) {
        const float* p = cls + gt * CATE;
        float best = p[0]; int bi = 0;
        #pragma unroll
        for (int i = 1; i < CATE; ++i) {
            float v = p[i];
            if (v > best) { best = v; bi = i; }   // strict > => first max, matches argmax
        }
        cid[gt] = bi;
    }
    for (int i = gt; i < nsums; i += gridDim.x * 256) sums[i] = 0.0f;
}

// One block = (batch b, 256-column chunk). Thread owns one column n.
// x[K] = feat column in VGPRs; W/bias via wave-uniform scalar loads.
// Writes e = exp(feat + relu(W@feat + b)) and accumulates per-row sums.
template<int K>
__global__ __launch_bounds__(256) void expert_exp_kernel(
    const float* __restrict__ feat,   // [B,K,NPTS]
    const float* __restrict__ W,      // [CATE,K,K]
    const float* __restrict__ bias,   // [CATE,K]
    const int*   __restrict__ cid,    // [B]
    float*       __restrict__ out,    // [B,K,NPTS] (exp values)
    float*       __restrict__ sums)   // [B*K]
{
    const int b = blockIdx.x >> 3;                     // 2048/256 = 8 chunks
    const int n = ((blockIdx.x & 7) << 8) + threadIdx.x;
    const int c = __builtin_amdgcn_readfirstlane(cid[b]);  // force SGPR -> s_load for W/bias
    const float* Wc = W + (size_t)c * K * K;
    const float* bc = bias + (size_t)c * K;
    const float* fb = feat + (size_t)b * K * NPTS + n;
    float*       ob = out  + (size_t)b * K * NPTS + n;

    float x[K];
    #pragma unroll
    for (int j = 0; j < K; ++j) x[j] = fb[(size_t)j * NPTS];

    __shared__ float part[K * 4];
    const int lane = threadIdx.x & 63;
    const int wid  = threadIdx.x >> 6;

    #pragma unroll 1
    for (int i = 0; i < K; ++i) {
        float acc = bc[i];
        #pragma unroll
        for (int j = 0; j < K; ++j) acc = fmaf(Wc[i * K + j], x[j], acc);
        float off = fmaxf(acc, 0.0f);
        // Logits bounded (|feat|max ~5.7, off <~ 4): exp w/o max-subtract is fp32-safe.
        float e = __expf(x[i] + off);
        ob[(size_t)i * NPTS] = e;

        float r = e;
        #pragma unroll
        for (int s = 32; s >= 1; s >>= 1) r += __shfl_xor(r, s, 64);
        if (lane == 0) part[i * 4 + wid] = r;
    }
    __syncthreads();
    if (threadIdx.x < K) {
        float s = part[threadIdx.x * 4 + 0] + part[threadIdx.x * 4 + 1]
                + part[threadIdx.x * 4 + 2] + part[threadIdx.x * 4 + 3];
        atomicAdd(&sums[b * K + threadIdx.x], s);   // 8 blocks/row contend: trivial
    }
}

// One block per row: scale 2048 floats by 1/rowsum, float4 vectorized.
__global__ __launch_bounds__(256) void normalize_kernel(
    float* __restrict__ out, const float* __restrict__ sums)
{
    const size_t row = blockIdx.x;
    const float inv = 1.0f / sums[row];
    float4* p = reinterpret_cast<float4*>(out + row * NPTS);
    #pragma unroll
    for (int k = 0; k < NPTS / 1024; ++k) {         // 2 iterations
        float4 v = p[k * 256 + threadIdx.x];
        v.x *= inv; v.y *= inv; v.z *= inv; v.w *= inv;
        p[k * 256 + threadIdx.x] = v;
    }
}

extern "C" void kernel_launch(void* const* d_in, const int* in_sizes, int n_in,
                              void* d_out, int out_size, void* d_ws, size_t ws_size,
                              hipStream_t stream)
{
    const float* feat1 = (const float*)d_in[0];
    const float* feat2 = (const float*)d_in[1];
    const float* feat3 = (const float*)d_in[2];
    const float* cls   = (const float*)d_in[3];
    const float* W1    = (const float*)d_in[4];
    const float* b1    = (const float*)d_in[5];
    const float* W2    = (const float*)d_in[6];
    const float* b2    = (const float*)d_in[7];
    const float* W3    = (const float*)d_in[8];
    const float* b3    = (const float*)d_in[9];
    float* out = (float*)d_out;

    // ws layout: cid int[128] @0, rowsums float[28672] @512
    int*   cid  = (int*)d_ws;
    float* sums = (float*)((char*)d_ws + 512);
    const int nrows1 = B_SZ * 32, nrows2 = B_SZ * 64, nrows3 = B_SZ * 128;
    const int nsums  = nrows1 + nrows2 + nrows3;     // 28672

    prep_kernel<<<112, 256, 0, stream>>>(cls, cid, sums, nsums);

    float* out1 = out;
    float* out2 = out + (size_t)nrows1 * NPTS;
    float* out3 = out + (size_t)(nrows1 + nrows2) * NPTS;
    float* outc = out + (size_t)nsums * NPTS;

    expert_exp_kernel<32><<<B_SZ * 8, 256, 0, stream>>>(feat1, W1, b1, cid, out1, sums);
    expert_exp_kernel<64><<<B_SZ * 8, 256, 0, stream>>>(feat2, W2, b2, cid, out2, sums + nrows1);
    expert_exp_kernel<128><<<B_SZ * 8, 256, 0, stream>>>(feat3, W3, b3, cid, out3, sums + nrows1 + nrows2);

    normalize_kernel<<<nsums, 256, 0, stream>>>(out, sums);

    hipMemcpyAsync(outc, cls, (size_t)B_SZ * CATE * sizeof(float),
                   hipMemcpyDeviceToDevice, stream);
}

// Round 3
// 791.685 us; speedup vs baseline: 1.4651x; 1.4651x over previous
//
#include <hip/hip_runtime.h>

#define B_SZ 128
#define NPTS 2048
#define CATE 55

// prep: per-batch argmax of cls_score -> cid; zero the row-sum scratch.
__global__ __launch_bounds__(256) void prep_kernel(
    const float* __restrict__ cls, int* __restrict__ cid,
    float* __restrict__ sums, int nsums)
{
    int gt = blockIdx.x * 256 + threadIdx.x;
    if (gt < B_SZ) {
        const float* p = cls + gt * CATE;
        float best = p[0]; int bi = 0;
        #pragma unroll
        for (int i = 1; i < CATE; ++i) {
            float v = p[i];
            if (v > best) { best = v; bi = i; }   // strict > => first max, matches argmax
        }
        cid[gt] = bi;
    }
    for (int i = gt; i < nsums; i += gridDim.x * 256) sums[i] = 0.0f;
}

// Block = (batch b, 64-column chunk). 256 threads = 64 cols x 4 row-groups
// (row-group == wave id, so W/bias indices are wave-uniform -> s_load).
// Feat tile [K x 64] staged in LDS; each thread computes K/4 rows in
// chunks of 8 accumulators -> max ~10 live floats/thread, NO spill
// (round-2 spill of x[K] cost 5x: WRITE 269MB vs 134MB, VALUBusy 20%).
template<int K>
__global__ __launch_bounds__(256) void expert_exp_kernel(
    const float* __restrict__ feat,   // [B,K,NPTS]
    const float* __restrict__ W,      // [CATE,K,K]
    const float* __restrict__ bias,   // [CATE,K]
    const int*   __restrict__ cid,    // [B]
    float*       __restrict__ out,    // [B,K,NPTS] (exp values)
    float*       __restrict__ sums)   // [B*K]
{
    constexpr int RT = K / 4;                       // rows per thread
    const int b     = blockIdx.x >> 5;              // 2048/64 = 32 chunks
    const int chunk = blockIdx.x & 31;
    const int col   = threadIdx.x & 63;             // lane == column
    const int rg    = __builtin_amdgcn_readfirstlane(threadIdx.x >> 6); // wave id, SGPR
    const int c     = __builtin_amdgcn_readfirstlane(cid[b]);

    const float* Wc = W + (size_t)c * K * K;
    const float* bc = bias + (size_t)c * K;
    const float* fb = feat + (size_t)b * K * NPTS + chunk * 64;
    float*       ob = out  + (size_t)b * K * NPTS + chunk * 64 + col;

    __shared__ float xs[K * 64];                    // K=128 -> 32 KB

    // Stage feat tile: float4, 16 rows per 256-thread pass, coalesced.
    {
        const int r0 = threadIdx.x >> 4;            // 0..15
        const int c4 = (threadIdx.x & 15) << 2;     // 0,4,..,60
        #pragma unroll
        for (int p = 0; p < K / 16; ++p) {
            const int r = p * 16 + r0;
            const float4 v = *(const float4*)(fb + (size_t)r * NPTS + c4);
            *(float4*)(&xs[r * 64 + c4]) = v;
        }
    }
    __syncthreads();

    const int i0 = rg * RT;
    #pragma unroll 1
    for (int ic = 0; ic < RT; ic += 8) {
        float acc[8];
        #pragma unroll
        for (int t = 0; t < 8; ++t) acc[t] = bc[i0 + ic + t];

        #pragma unroll 4
        for (int j = 0; j < K; ++j) {
            const float xv = xs[j * 64 + col];      // stride-1: 2-way alias = free
            #pragma unroll
            for (int t = 0; t < 8; ++t)
                acc[t] = fmaf(Wc[(size_t)(i0 + ic + t) * K + j], xv, acc[t]);
        }

        #pragma unroll
        for (int t = 0; t < 8; ++t) {
            const int i = i0 + ic + t;
            const float x = xs[i * 64 + col];
            // Logits bounded (|feat|max ~5.7, off <~4): exp w/o max-sub is fp32-safe.
            const float e = __expf(x + fmaxf(acc[t], 0.0f));
            ob[(size_t)i * NPTS] = e;
            float r = e;
            #pragma unroll
            for (int s = 32; s >= 1; s >>= 1) r += __shfl_xor(r, s, 64);
            if (col == 0) atomicAdd(&sums[b * K + i], r);   // 32 adds/row total
        }
    }
}

// One block per row: scale 2048 floats by 1/rowsum, float4 vectorized.
__global__ __launch_bounds__(256) void normalize_kernel(
    float* __restrict__ out, const float* __restrict__ sums)
{
    const size_t row = blockIdx.x;
    const float inv = 1.0f / sums[row];
    float4* p = reinterpret_cast<float4*>(out + row * NPTS);
    #pragma unroll
    for (int k = 0; k < NPTS / 1024; ++k) {         // 2 iterations
        float4 v = p[k * 256 + threadIdx.x];
        v.x *= inv; v.y *= inv; v.z *= inv; v.w *= inv;
        p[k * 256 + threadIdx.x] = v;
    }
}

extern "C" void kernel_launch(void* const* d_in, const int* in_sizes, int n_in,
                              void* d_out, int out_size, void* d_ws, size_t ws_size,
                              hipStream_t stream)
{
    const float* feat1 = (const float*)d_in[0];
    const float* feat2 = (const float*)d_in[1];
    const float* feat3 = (const float*)d_in[2];
    const float* cls   = (const float*)d_in[3];
    const float* W1    = (const float*)d_in[4];
    const float* b1    = (const float*)d_in[5];
    const float* W2    = (const float*)d_in[6];
    const float* b2    = (const float*)d_in[7];
    const float* W3    = (const float*)d_in[8];
    const float* b3    = (const float*)d_in[9];
    float* out = (float*)d_out;

    // ws layout: cid int[128] @0, rowsums float[28672] @512
    int*   cid  = (int*)d_ws;
    float* sums = (float*)((char*)d_ws + 512);
    const int nrows1 = B_SZ * 32, nrows2 = B_SZ * 64, nrows3 = B_SZ * 128;
    const int nsums  = nrows1 + nrows2 + nrows3;     // 28672

    prep_kernel<<<112, 256, 0, stream>>>(cls, cid, sums, nsums);

    float* out1 = out;
    float* out2 = out + (size_t)nrows1 * NPTS;
    float* out3 = out + (size_t)(nrows1 + nrows2) * NPTS;
    float* outc = out + (size_t)nsums * NPTS;

    expert_exp_kernel<32><<<B_SZ * 32, 256, 0, stream>>>(feat1, W1, b1, cid, out1, sums);
    expert_exp_kernel<64><<<B_SZ * 32, 256, 0, stream>>>(feat2, W2, b2, cid, out2, sums + nrows1);
    expert_exp_kernel<128><<<B_SZ * 32, 256, 0, stream>>>(feat3, W3, b3, cid, out3, sums + nrows1 + nrows2);

    normalize_kernel<<<nsums, 256, 0, stream>>>(out, sums);

    hipMemcpyAsync(outc, cls, (size_t)B_SZ * CATE * sizeof(float),
                   hipMemcpyDeviceToDevice, stream);
}